// Round 11
// baseline (3017.248 us; speedup 1.0000x reference)
//
#include <hip/hip_runtime.h>
#include <hip/hip_bf16.h>

// Problem dims
#define V_    10000
#define ENC_  2048
#define D_    512
#define B_    128
#define L_    64
#define T_    63          // L-1 timesteps
#define M_    (B_ * L_ - B_)   // 8064 rows (b*63 + t)
#define G_    (3 * D_)    // 1536 gate width
#define LOGITS_SZ ((long)M_ * V_)   // 80,640,000

typedef __bf16 bf16x8_t __attribute__((ext_vector_type(8)));
typedef float  f32x4_t  __attribute__((ext_vector_type(4)));
typedef short  s16x8_t  __attribute__((ext_vector_type(8)));
typedef unsigned long long ull_t;

typedef __attribute__((address_space(3))) char*       lds_cptr_t;
typedef const __attribute__((address_space(1))) char* glb_cptr_t;

__device__ __forceinline__ void gload_lds16(const void* g, void* l) {
  __builtin_amdgcn_global_load_lds((glb_cptr_t)g, (lds_cptr_t)l, 16, 0, 0);
}
__device__ __forceinline__ float bf2f(short s) {
  return __uint_as_float(((unsigned)(unsigned short)s) << 16);
}
__device__ __forceinline__ short f2bf(float f) {
  __hip_bfloat16 h = __float2bfloat16(f);  // RNE
  return *reinterpret_cast<short*>(&h);
}
__device__ __forceinline__ s16x8_t cvt8(const float* p) {
  f32x4_t lo = *reinterpret_cast<const f32x4_t*>(p);
  f32x4_t hi = *reinterpret_cast<const f32x4_t*>(p + 4);
  s16x8_t r;
#pragma unroll
  for (int e = 0; e < 4; e++) { r[e] = f2bf(lo[e]); r[4 + e] = f2bf(hi[e]); }
  return r;
}
__device__ __forceinline__ float sigmoidf_(float x) {
  return 1.0f / (1.0f + __expf(-x));
}
__device__ __forceinline__ bf16x8_t lds_frag(const short* p) {
  return __builtin_bit_cast(bf16x8_t, *reinterpret_cast<const s16x8_t*>(p));
}

// ---------------- fused f32 -> bf16 converts (5 segments, 1 launch) ----------------
__global__ void GG_cvt5(const float* __restrict__ whh, __hip_bfloat16* __restrict__ dwhh,
                        const float* __restrict__ wih, __hip_bfloat16* __restrict__ dwih,
                        const float* __restrict__ wemb, __hip_bfloat16* __restrict__ dwemb,
                        const float* __restrict__ winit, __hip_bfloat16* __restrict__ dwinit,
                        const float* __restrict__ gf, __hip_bfloat16* __restrict__ dgf) {
  const int i = blockIdx.x * blockDim.x + threadIdx.x;
  const float* s; __hip_bfloat16* d; int off;
  if (i < 98304)        { s = whh;   d = dwhh;   off = i; }
  else if (i < 196608)  { s = wih;   d = dwih;   off = i - 98304; }
  else if (i < 836608)  { s = wemb;  d = dwemb;  off = i - 196608; }
  else if (i < 967680)  { s = winit; d = dwinit; off = i - 836608; }
  else                  { s = gf;    d = dgf;    off = i - 967680; }
  s16x8_t v = cvt8(s + (long)off * 8);
  *reinterpret_cast<s16x8_t*>(d + (long)off * 8) = v;
}

__global__ void GG_cvt_kernel(const float* __restrict__ src,
                              __hip_bfloat16* __restrict__ dst, int n8) {
  int i = blockIdx.x * blockDim.x + threadIdx.x;
  if (i < n8) {
    s16x8_t v = cvt8(src + (long)i * 8);
    *reinterpret_cast<s16x8_t*>(dst + (long)i * 8) = v;
  }
}

// ---------------- h0 GEMM: hfull[b][0][:] = tanh(gf @ W_init^T + b_init) ----------------
__global__ __launch_bounds__(256) void GG_gemm_h0(
    const __hip_bfloat16* __restrict__ gfB,     // [128][2048] bf16
    const __hip_bfloat16* __restrict__ WinitB,  // [512][2048] bf16
    const float* __restrict__ binit,            // [512] f32
    __hip_bfloat16* __restrict__ hfull) {       // [B][64][512]
  __shared__ short sA[128 * 64];
  __shared__ short sB[128 * 64];
  const int lane = threadIdx.x & 63;
  const int wave = threadIdx.x >> 6;
  const int n0 = blockIdx.x * 128;
  const int srow = lane >> 3;
  const int scol = (lane & 7) * 8;

  f32x4_t acc[4][4] = {};

  const __hip_bfloat16* aptr[4];
  const __hip_bfloat16* bptr[4];
#pragma unroll
  for (int i = 0; i < 4; i++) {
    const int r = (wave * 4 + i) * 8 + srow;
    aptr[i] = gfB + (long)r * ENC_ + scol;
    bptr[i] = WinitB + (long)(n0 + r) * ENC_ + scol;
  }

  const int wm = (wave >> 1) * 64;
  const int wn = (wave & 1) * 64;
  const int fr = lane & 15;
  const int fk = (lane >> 4) * 8;

  for (int kt = 0; kt < 32; kt++) {
    __syncthreads();
#pragma unroll
    for (int i = 0; i < 4; i++) {
      const int chunk = wave * 4 + i;
      gload_lds16(aptr[i] + kt * 64, sA + chunk * 512);
      gload_lds16(bptr[i] + kt * 64, sB + chunk * 512);
    }
    __syncthreads();
#pragma unroll
    for (int kk = 0; kk < 2; kk++) {
      bf16x8_t a[4], b[4];
#pragma unroll
      for (int i = 0; i < 4; i++) {
        a[i] = lds_frag(sA + (wm + i * 16 + fr) * 64 + kk * 32 + fk);
        b[i] = lds_frag(sB + (wn + i * 16 + fr) * 64 + kk * 32 + fk);
      }
#pragma unroll
      for (int i = 0; i < 4; i++)
#pragma unroll
        for (int j = 0; j < 4; j++)
          acc[i][j] = __builtin_amdgcn_mfma_f32_16x16x32_bf16(a[i], b[j], acc[i][j], 0, 0, 0);
    }
  }

  const int fq = lane >> 4;
#pragma unroll
  for (int j = 0; j < 4; j++) {
    const int n = n0 + wn + j * 16 + fr;
    const float bv = binit[n];
#pragma unroll
    for (int i = 0; i < 4; i++)
#pragma unroll
      for (int rr = 0; rr < 4; rr++) {
        const int m = wm + i * 16 + fq * 4 + rr;
        hfull[(long)m * 64 * 512 + n] = __float2bfloat16(tanhf(acc[i][j][rr] + bv));
      }
  }
}

// ---------------- gi GEMM: gi = gather(W_embed,cap) @ W_ih^T + b_ih ----------------
__global__ __launch_bounds__(256) void GG_gemm_gi(
    const __hip_bfloat16* __restrict__ WembB,  // [V][512] bf16
    const int* __restrict__ cap,               // [B][L] int32
    const __hip_bfloat16* __restrict__ WihB,   // [G][512] bf16
    const float* __restrict__ bias,            // [G] f32
    __hip_bfloat16* __restrict__ C) {          // [M][G]
  __shared__ short sA[128 * 64];
  __shared__ short sB[128 * 64];
  const int lane = threadIdx.x & 63;
  const int wave = threadIdx.x >> 6;
  const int m0 = blockIdx.y * 128;
  const int n0 = blockIdx.x * 128;
  const int srow = lane >> 3;
  const int scol = (lane & 7) * 8;

  f32x4_t acc[4][4] = {};

  const __hip_bfloat16* aptr[4];
  const __hip_bfloat16* bptr[4];
#pragma unroll
  for (int i = 0; i < 4; i++) {
    const int r = (wave * 4 + i) * 8 + srow;
    const int bt = m0 + r;
    const int bb = bt / 63;
    const int tt = bt - bb * 63;
    aptr[i] = WembB + (long)cap[bb * L_ + tt] * 512 + scol;
    bptr[i] = WihB + (long)(n0 + r) * 512 + scol;
  }

  const int wm = (wave >> 1) * 64;
  const int wn = (wave & 1) * 64;
  const int fr = lane & 15;
  const int fk = (lane >> 4) * 8;

  for (int kt = 0; kt < 8; kt++) {
    __syncthreads();
#pragma unroll
    for (int i = 0; i < 4; i++) {
      const int chunk = wave * 4 + i;
      gload_lds16(aptr[i] + kt * 64, sA + chunk * 512);
      gload_lds16(bptr[i] + kt * 64, sB + chunk * 512);
    }
    __syncthreads();
#pragma unroll
    for (int kk = 0; kk < 2; kk++) {
      bf16x8_t a[4], b[4];
#pragma unroll
      for (int i = 0; i < 4; i++) {
        a[i] = lds_frag(sA + (wm + i * 16 + fr) * 64 + kk * 32 + fk);
        b[i] = lds_frag(sB + (wn + i * 16 + fr) * 64 + kk * 32 + fk);
      }
#pragma unroll
      for (int i = 0; i < 4; i++)
#pragma unroll
        for (int j = 0; j < 4; j++)
          acc[i][j] = __builtin_amdgcn_mfma_f32_16x16x32_bf16(a[i], b[j], acc[i][j], 0, 0, 0);
    }
  }

  const int fq = lane >> 4;
#pragma unroll
  for (int j = 0; j < 4; j++) {
    const int n = n0 + wn + j * 16 + fr;
    const float bv = bias[n];
#pragma unroll
    for (int i = 0; i < 4; i++)
#pragma unroll
      for (int rr = 0; rr < 4; rr++) {
        const int m = m0 + wm + i * 16 + fq * 4 + rr;
        C[(long)m * G_ + n] = __float2bfloat16(acc[i][j][rr] + bv);
      }
  }
}

// ---------------- logits GEMM: logits = hs @ W_fc^T + b_fc ----------------
template <bool BBF16>
__global__ __launch_bounds__(256) void GG_gemm_logits(
    const __hip_bfloat16* __restrict__ hfull,  // [B][64][512]
    const void* __restrict__ Bsrc,             // W_fc bf16 or f32 [V][512]
    const float* __restrict__ bias,            // [V] f32
    float* __restrict__ C) {                   // [M][V]
  const int flat = blockIdx.x;
  const int xcd = flat & 7;
  const int s = flat >> 3;           // 0..629
  const int col = xcd * 10 + s % 10; // 0..79
  const int row = s / 10;            // 0..62
  if (col >= 79) return;
  const int m0 = row * 128;
  const int n0 = col * 128;

  __shared__ short sA[128 * 64];
  __shared__ short sB[128 * 64];
  const int lane = threadIdx.x & 63;
  const int wave = threadIdx.x >> 6;
  const int srow = lane >> 3;
  const int scol = (lane & 7) * 8;

  f32x4_t acc[4][4] = {};

  const __hip_bfloat16* aptr[4];
  const __hip_bfloat16* bptrB[4];
  const float* bptrF[4];
#pragma unroll
  for (int i = 0; i < 4; i++) {
    const int r = (wave * 4 + i) * 8 + srow;
    const int m = m0 + r;
    const int bb = m / 63;
    const int tt = m - bb * 63;
    aptr[i] = hfull + ((long)bb * 64 + tt + 1) * 512 + scol;
    int nrow = n0 + r;
    nrow = (nrow < V_) ? nrow : (V_ - 1);
    if constexpr (BBF16) bptrB[i] = (const __hip_bfloat16*)Bsrc + (long)nrow * 512 + scol;
    else                 bptrF[i] = (const float*)Bsrc + (long)nrow * 512 + scol;
  }

  const int wm = (wave >> 1) * 64;
  const int wn = (wave & 1) * 64;
  const int fr = lane & 15;
  const int fk = (lane >> 4) * 8;

  for (int kt = 0; kt < 8; kt++) {
    s16x8_t vb[4];
    if constexpr (!BBF16) {
#pragma unroll
      for (int i = 0; i < 4; i++) vb[i] = cvt8(bptrF[i] + kt * 64);
    }
    __syncthreads();
#pragma unroll
    for (int i = 0; i < 4; i++) {
      const int chunk = wave * 4 + i;
      gload_lds16(aptr[i] + kt * 64, sA + chunk * 512);
      if constexpr (BBF16)
        gload_lds16(bptrB[i] + kt * 64, sB + chunk * 512);
      else
        *reinterpret_cast<s16x8_t*>(sB + chunk * 512 + lane * 8) = vb[i];
    }
    __syncthreads();
#pragma unroll
    for (int kk = 0; kk < 2; kk++) {
      bf16x8_t a[4], b[4];
#pragma unroll
      for (int i = 0; i < 4; i++) {
        a[i] = lds_frag(sA + (wm + i * 16 + fr) * 64 + kk * 32 + fk);
        b[i] = lds_frag(sB + (wn + i * 16 + fr) * 64 + kk * 32 + fk);
      }
#pragma unroll
      for (int i = 0; i < 4; i++)
#pragma unroll
        for (int j = 0; j < 4; j++)
          acc[i][j] = __builtin_amdgcn_mfma_f32_16x16x32_bf16(a[i], b[j], acc[i][j], 0, 0, 0);
    }
  }

  const int fq = lane >> 4;
#pragma unroll
  for (int j = 0; j < 4; j++) {
    const int n = n0 + wn + j * 16 + fr;
    if (n >= V_) continue;
    const float bv = bias[n];
#pragma unroll
    for (int i = 0; i < 4; i++)
#pragma unroll
      for (int rr = 0; rr < 4; rr++) {
        const int m = m0 + wm + i * 16 + fq * 4 + rr;
        C[(long)m * V_ + n] = acc[i][j][rr] + bv;
      }
  }
}

// ---------------- GRU scan, v6: batch-local blocks, ZERO inter-block sync ----
// 8 blocks x 512 thr (8 waves). Block owns batch rows [blk*16, blk*16+16) and
// the FULL D=512 -> h never crosses a CU boundary. Whh (1.5 MB bf16) streamed
// from L2 each step, direct global->reg (L2-resident per XCD after step 0).
// Wave w owns d-strip [w*64, w*64+64): 3 gates x 4 N-tiles = 12 MFMA tiles.
// h[t] shared between waves via 16 KB XOR-swizzled LDS tile; 2 intra-block
// barriers per step. h[t+1] also streamed to global for the logits kernel.
__global__ __launch_bounds__(512) void GG_scan_local(
    __hip_bfloat16* __restrict__ hfull,       // [B][64][512]
    const __hip_bfloat16* __restrict__ gi,    // [M][G]
    const __hip_bfloat16* __restrict__ WhhB,  // [G][512] bf16
    const float* __restrict__ bhh) {          // [G] f32
  __shared__ short sH[16 * 512];  // 16 KB, h[t], XOR-swizzled 16B granules
  const int lane = threadIdx.x & 63;
  const int wave = threadIdx.x >> 6;   // 0..7
  const int fr = lane & 15;
  const int g4 = lane >> 4;            // 0..3
  const int b0 = blockIdx.x * 16;
  const int dw = wave * 64;

  // stage h0 rows into sH: linear LDS dest, swizzled global source granules
  for (int r = wave * 2; r < wave * 2 + 2; r++)
    gload_lds16(hfull + ((long)(b0 + r) * 64) * 512 + (lane ^ (r & 7)) * 8,
                sH + r * 512);

  const short* Ws  = (const short*)WhhB;
  const short* gis = (const short*)gi;

  // per-lane constants: bias + B row bases (fixed across t)
  float bh[3][4];
  const short* bbase[3][4];
#pragma unroll
  for (int g = 0; g < 3; g++)
#pragma unroll
    for (int tt = 0; tt < 4; tt++) {
      const int d = dw + tt * 16 + fr;
      bh[g][tt] = bhh[g * 512 + d];
      bbase[g][tt] = Ws + (long)(g * 512 + d) * 512 + g4 * 8;
    }

  // hp register-carried; init from h0
  float hp[4][4];  // [tt][rr]
#pragma unroll
  for (int tt = 0; tt < 4; tt++)
#pragma unroll
    for (int rr = 0; rr < 4; rr++) {
      const int b = b0 + g4 * 4 + rr;
      const int d = dw + tt * 16 + fr;
      hp[tt][rr] = bf2f(*(const short*)&hfull[((long)b * 64) * 512 + d]);
    }

  asm volatile("s_waitcnt vmcnt(0)" ::: "memory");
  __syncthreads();  // sH = h[0] ready

  for (int t = 0; t < T_; t++) {
    // A-frags from sH: lane row fr, k-granule kt*4+g4 (XOR-deswizzled)
    f32x4_t a[16];
#pragma unroll
    for (int kt = 0; kt < 16; kt++) {
      const int kg = (kt * 4 + g4) ^ (fr & 7);
      a[kt] = *reinterpret_cast<const f32x4_t*>((const char*)sH + fr * 1024 + kg * 16);
    }
    __syncthreads();  // all waves done READING h[t] (epilogue may overwrite)

    // gh = h[t] @ Whh^T for wave's 12 gate-tiles; B direct from L2
    f32x4_t acc[3][4] = {};
#pragma unroll
    for (int g = 0; g < 3; g++)
#pragma unroll
      for (int tt = 0; tt < 4; tt++) {
        const short* bp = bbase[g][tt];
        s16x8_t bf[16];
#pragma unroll
        for (int kt = 0; kt < 16; kt++)
          bf[kt] = *reinterpret_cast<const s16x8_t*>(bp + kt * 32);
#pragma unroll
        for (int kt = 0; kt < 16; kt++)
          acc[g][tt] = __builtin_amdgcn_mfma_f32_16x16x32_bf16(
              __builtin_bit_cast(bf16x8_t, a[kt]),
              __builtin_bit_cast(bf16x8_t, bf[kt]), acc[g][tt], 0, 0, 0);
      }

    // fused gates; write h[t+1] to sH (swizzled) + global (for logits)
#pragma unroll
    for (int tt = 0; tt < 4; tt++) {
      const int d = dw + tt * 16 + fr;
#pragma unroll
      for (int rr = 0; rr < 4; rr++) {
        const int m = g4 * 4 + rr;
        const int b = b0 + m;
        const long gbase = ((long)b * T_ + t) * (long)G_ + d;
        const float ir  = bf2f(gis[gbase]);
        const float iz  = bf2f(gis[gbase + 512]);
        const float in_ = bf2f(gis[gbase + 1024]);
        const float rg = sigmoidf_(ir + acc[0][tt][rr] + bh[0][tt]);
        const float zg = sigmoidf_(iz + acc[1][tt][rr] + bh[1][tt]);
        const float ng = tanhf(in_ + rg * (acc[2][tt][rr] + bh[2][tt]));
        const short hnb = f2bf((1.f - zg) * ng + zg * hp[tt][rr]);
        hp[tt][rr] = bf2f(hnb);
        *(short*)((char*)sH + m * 1024 + ((d * 2) ^ ((m & 7) << 4))) = hnb;
        *(short*)&hfull[((long)b * 64 + t + 1) * 512 + d] = hnb;
      }
    }
    __syncthreads();  // sH = h[t+1] complete for all waves
  }
}

// ---------------- tail: out[LOGITS_SZ + b] = f32(len[b] - 1) ----------------
__global__ void GG_tail_kernel(const int* __restrict__ lens, float* __restrict__ out) {
  const int b = threadIdx.x;
  if (b < B_) out[LOGITS_SZ + b] = (float)(lens[b] - 1);
}

extern "C" void kernel_launch(void* const* d_in, const int* in_sizes, int n_in,
                              void* d_out, int out_size, void* d_ws, size_t ws_size,
                              hipStream_t stream) {
  const float* gf      = (const float*)d_in[0];
  const int*   cap     = (const int*)d_in[1];
  const int*   lens    = (const int*)d_in[2];
  const float* W_embed = (const float*)d_in[3];
  const float* W_init  = (const float*)d_in[4];
  const float* b_init  = (const float*)d_in[5];
  const float* W_ih    = (const float*)d_in[6];
  const float* W_hh    = (const float*)d_in[7];
  const float* b_ih    = (const float*)d_in[8];
  const float* b_hh    = (const float*)d_in[9];
  const float* W_fc    = (const float*)d_in[10];
  const float* b_fc    = (const float*)d_in[11];
  float* out = (float*)d_out;

  // d_out scratch (all consumed before the logits GEMM writes d_out):
  char* ob = (char*)d_out;
  __hip_bfloat16* gi_ws  = (__hip_bfloat16*)ob;               // [0, 24,772,608)
  __hip_bfloat16* WhhB   = (__hip_bfloat16*)(ob + 25165824);  // 1.5 MB
  __hip_bfloat16* WihB   = (__hip_bfloat16*)(ob + 27262976);  // 1.5 MB
  __hip_bfloat16* WembB  = (__hip_bfloat16*)(ob + 29360128);  // 10 MB
  __hip_bfloat16* WinitB = (__hip_bfloat16*)(ob + 40894464);  // 2 MB
  __hip_bfloat16* gfB    = (__hip_bfloat16*)(ob + 43253760);  // 0.5 MB

  // ws: hfull [B][64][512] bf16 (slot 0 = h0, slot t+1 = h_t) + WfcB
  __hip_bfloat16* hfull = (__hip_bfloat16*)d_ws;
  __hip_bfloat16* WfcB  = (__hip_bfloat16*)((char*)d_ws + 8388608);
  const bool big_ws = ws_size >= (size_t)(8388608 + 10240000);

  // 1. weight/input converts to bf16 (fused: 3908 * 256 covers all 5 segments)
  GG_cvt5<<<dim3(3908), 256, 0, stream>>>(W_hh, WhhB, W_ih, WihB, W_embed, WembB,
                                          W_init, WinitB, gf, gfB);
  if (big_ws)
    GG_cvt_kernel<<<dim3((V_ * D_ / 8 + 255) / 256), 256, 0, stream>>>(W_fc, WfcB, V_ * D_ / 8);

  // 2. h0 -> hfull slot 0 (MFMA GEMM, 4 blocks)
  GG_gemm_h0<<<dim3(4), 256, 0, stream>>>(gfB, WinitB, b_init, hfull);

  // 3. gi = gather(W_embed, cap) @ W_ih^T + b_ih
  GG_gemm_gi<<<dim3(G_ / 128, M_ / 128), 256, 0, stream>>>(WembB, cap, WihB, b_ih, gi_ws);

  // 4. GRU scan: 8 batch-local blocks, zero inter-block sync
  GG_scan_local<<<dim3(8), 512, 0, stream>>>(hfull, gi_ws, WhhB, b_hh);

  // 5. logits (XCD-banded swizzle, 5040 = 8*10*63 padded blocks)
  if (big_ws)
    GG_gemm_logits<true><<<dim3(5040), 256, 0, stream>>>(hfull, WfcB, b_fc, out);
  else
    GG_gemm_logits<false><<<dim3(5040), 256, 0, stream>>>(hfull, W_fc, b_fc, out);

  // 6. second output
  GG_tail_kernel<<<dim3(1), 128, 0, stream>>>(lens, out);
}

// Round 13
// 597.408 us; speedup vs baseline: 5.0506x; 5.0506x over previous
//
#include <hip/hip_runtime.h>
#include <hip/hip_bf16.h>

// Problem dims
#define V_    10000
#define ENC_  2048
#define D_    512
#define B_    128
#define L_    64
#define T_    63          // L-1 timesteps
#define M_    (B_ * L_ - B_)   // 8064 rows (b*63 + t)
#define G_    (3 * D_)    // 1536 gate width
#define LOGITS_SZ ((long)M_ * V_)   // 80,640,000
#define SCAN_NB 64        // 2 batch-halves x 32 d-strips

typedef __bf16 bf16x8_t __attribute__((ext_vector_type(8)));
typedef float  f32x4_t  __attribute__((ext_vector_type(4)));
typedef short  s16x8_t  __attribute__((ext_vector_type(8)));
typedef unsigned u32x4_t __attribute__((ext_vector_type(4)));
typedef unsigned long long ull_t;

typedef __attribute__((address_space(3))) char*       lds_cptr_t;
typedef const __attribute__((address_space(1))) char* glb_cptr_t;

__device__ __forceinline__ void gload_lds16(const void* g, void* l) {
  __builtin_amdgcn_global_load_lds((glb_cptr_t)g, (lds_cptr_t)l, 16, 0, 0);
}
__device__ __forceinline__ float bf2f(short s) {
  return __uint_as_float(((unsigned)(unsigned short)s) << 16);
}
__device__ __forceinline__ short f2bf(float f) {
  __hip_bfloat16 h = __float2bfloat16(f);  // RNE
  return *reinterpret_cast<short*>(&h);
}
__device__ __forceinline__ s16x8_t cvt8(const float* p) {
  f32x4_t lo = *reinterpret_cast<const f32x4_t*>(p);
  f32x4_t hi = *reinterpret_cast<const f32x4_t*>(p + 4);
  s16x8_t r;
#pragma unroll
  for (int e = 0; e < 4; e++) { r[e] = f2bf(lo[e]); r[4 + e] = f2bf(hi[e]); }
  return r;
}
__device__ __forceinline__ float sigmoidf_(float x) {
  return 1.0f / (1.0f + __expf(-x));
}
__device__ __forceinline__ bf16x8_t lds_frag(const short* p) {
  return __builtin_bit_cast(bf16x8_t, *reinterpret_cast<const s16x8_t*>(p));
}

// ---------------- fused f32 -> bf16 converts (5 segments, 1 launch) ----------------
__global__ void GG_cvt5(const float* __restrict__ whh, __hip_bfloat16* __restrict__ dwhh,
                        const float* __restrict__ wih, __hip_bfloat16* __restrict__ dwih,
                        const float* __restrict__ wemb, __hip_bfloat16* __restrict__ dwemb,
                        const float* __restrict__ winit, __hip_bfloat16* __restrict__ dwinit,
                        const float* __restrict__ gf, __hip_bfloat16* __restrict__ dgf) {
  const int i = blockIdx.x * blockDim.x + threadIdx.x;
  const float* s; __hip_bfloat16* d; int off;
  if (i < 98304)        { s = whh;   d = dwhh;   off = i; }
  else if (i < 196608)  { s = wih;   d = dwih;   off = i - 98304; }
  else if (i < 836608)  { s = wemb;  d = dwemb;  off = i - 196608; }
  else if (i < 967680)  { s = winit; d = dwinit; off = i - 836608; }
  else                  { s = gf;    d = dgf;    off = i - 967680; }
  s16x8_t v = cvt8(s + (long)off * 8);
  *reinterpret_cast<s16x8_t*>(d + (long)off * 8) = v;
}

__global__ void GG_cvt_kernel(const float* __restrict__ src,
                              __hip_bfloat16* __restrict__ dst, int n8) {
  int i = blockIdx.x * blockDim.x + threadIdx.x;
  if (i < n8) {
    s16x8_t v = cvt8(src + (long)i * 8);
    *reinterpret_cast<s16x8_t*>(dst + (long)i * 8) = v;
  }
}

// ---------------- h0 GEMM -> hfull[0][b][:] (t-major layout) ----------------
__global__ __launch_bounds__(256) void GG_gemm_h0(
    const __hip_bfloat16* __restrict__ gfB,     // [128][2048] bf16
    const __hip_bfloat16* __restrict__ WinitB,  // [512][2048] bf16
    const float* __restrict__ binit,            // [512] f32
    __hip_bfloat16* __restrict__ hfull) {       // [64][128][512] t-major
  __shared__ short sA[128 * 64];
  __shared__ short sB[128 * 64];
  const int lane = threadIdx.x & 63;
  const int wave = threadIdx.x >> 6;
  const int n0 = blockIdx.x * 128;
  const int srow = lane >> 3;
  const int scol = (lane & 7) * 8;

  f32x4_t acc[4][4] = {};

  const __hip_bfloat16* aptr[4];
  const __hip_bfloat16* bptr[4];
#pragma unroll
  for (int i = 0; i < 4; i++) {
    const int r = (wave * 4 + i) * 8 + srow;
    aptr[i] = gfB + (long)r * ENC_ + scol;
    bptr[i] = WinitB + (long)(n0 + r) * ENC_ + scol;
  }

  const int wm = (wave >> 1) * 64;
  const int wn = (wave & 1) * 64;
  const int fr = lane & 15;
  const int fk = (lane >> 4) * 8;

  for (int kt = 0; kt < 32; kt++) {
    __syncthreads();
#pragma unroll
    for (int i = 0; i < 4; i++) {
      const int chunk = wave * 4 + i;
      gload_lds16(aptr[i] + kt * 64, sA + chunk * 512);
      gload_lds16(bptr[i] + kt * 64, sB + chunk * 512);
    }
    __syncthreads();
#pragma unroll
    for (int kk = 0; kk < 2; kk++) {
      bf16x8_t a[4], b[4];
#pragma unroll
      for (int i = 0; i < 4; i++) {
        a[i] = lds_frag(sA + (wm + i * 16 + fr) * 64 + kk * 32 + fk);
        b[i] = lds_frag(sB + (wn + i * 16 + fr) * 64 + kk * 32 + fk);
      }
#pragma unroll
      for (int i = 0; i < 4; i++)
#pragma unroll
        for (int j = 0; j < 4; j++)
          acc[i][j] = __builtin_amdgcn_mfma_f32_16x16x32_bf16(a[i], b[j], acc[i][j], 0, 0, 0);
    }
  }

  const int fq = lane >> 4;
#pragma unroll
  for (int j = 0; j < 4; j++) {
    const int n = n0 + wn + j * 16 + fr;
    const float bv = binit[n];
#pragma unroll
    for (int i = 0; i < 4; i++)
#pragma unroll
      for (int rr = 0; rr < 4; rr++) {
        const int m = wm + i * 16 + fq * 4 + rr;
        hfull[(long)m * 512 + n] = __float2bfloat16(tanhf(acc[i][j][rr] + bv));
      }
  }
}

// ---------------- gi GEMM: gi = gather(W_embed,cap) @ W_ih^T + b_ih ----------------
__global__ __launch_bounds__(256) void GG_gemm_gi(
    const __hip_bfloat16* __restrict__ WembB,  // [V][512] bf16
    const int* __restrict__ cap,               // [B][L] int32
    const __hip_bfloat16* __restrict__ WihB,   // [G][512] bf16
    const float* __restrict__ bias,            // [G] f32
    __hip_bfloat16* __restrict__ C) {          // [M][G]
  __shared__ short sA[128 * 64];
  __shared__ short sB[128 * 64];
  const int lane = threadIdx.x & 63;
  const int wave = threadIdx.x >> 6;
  const int m0 = blockIdx.y * 128;
  const int n0 = blockIdx.x * 128;
  const int srow = lane >> 3;
  const int scol = (lane & 7) * 8;

  f32x4_t acc[4][4] = {};

  const __hip_bfloat16* aptr[4];
  const __hip_bfloat16* bptr[4];
#pragma unroll
  for (int i = 0; i < 4; i++) {
    const int r = (wave * 4 + i) * 8 + srow;
    const int bt = m0 + r;
    const int bb = bt / 63;
    const int tt = bt - bb * 63;
    aptr[i] = WembB + (long)cap[bb * L_ + tt] * 512 + scol;
    bptr[i] = WihB + (long)(n0 + r) * 512 + scol;
  }

  const int wm = (wave >> 1) * 64;
  const int wn = (wave & 1) * 64;
  const int fr = lane & 15;
  const int fk = (lane >> 4) * 8;

  for (int kt = 0; kt < 8; kt++) {
    __syncthreads();
#pragma unroll
    for (int i = 0; i < 4; i++) {
      const int chunk = wave * 4 + i;
      gload_lds16(aptr[i] + kt * 64, sA + chunk * 512);
      gload_lds16(bptr[i] + kt * 64, sB + chunk * 512);
    }
    __syncthreads();
#pragma unroll
    for (int kk = 0; kk < 2; kk++) {
      bf16x8_t a[4], b[4];
#pragma unroll
      for (int i = 0; i < 4; i++) {
        a[i] = lds_frag(sA + (wm + i * 16 + fr) * 64 + kk * 32 + fk);
        b[i] = lds_frag(sB + (wn + i * 16 + fr) * 64 + kk * 32 + fk);
      }
#pragma unroll
      for (int i = 0; i < 4; i++)
#pragma unroll
        for (int j = 0; j < 4; j++)
          acc[i][j] = __builtin_amdgcn_mfma_f32_16x16x32_bf16(a[i], b[j], acc[i][j], 0, 0, 0);
    }
  }

  const int fq = lane >> 4;
#pragma unroll
  for (int j = 0; j < 4; j++) {
    const int n = n0 + wn + j * 16 + fr;
    const float bv = bias[n];
#pragma unroll
    for (int i = 0; i < 4; i++)
#pragma unroll
      for (int rr = 0; rr < 4; rr++) {
        const int m = m0 + wm + i * 16 + fq * 4 + rr;
        C[(long)m * G_ + n] = __float2bfloat16(acc[i][j][rr] + bv);
      }
  }
}

// ---------------- logits GEMM: logits = hs @ W_fc^T + b_fc ----------------
template <bool BBF16>
__global__ __launch_bounds__(256) void GG_gemm_logits(
    const __hip_bfloat16* __restrict__ hfull,  // [64][128][512] t-major
    const void* __restrict__ Bsrc,             // W_fc bf16 or f32 [V][512]
    const float* __restrict__ bias,            // [V] f32
    float* __restrict__ C) {                   // [M][V]
  const int flat = blockIdx.x;
  const int xcd = flat & 7;
  const int s = flat >> 3;           // 0..629
  const int col = xcd * 10 + s % 10; // 0..79
  const int row = s / 10;            // 0..62
  if (col >= 79) return;
  const int m0 = row * 128;
  const int n0 = col * 128;

  __shared__ short sA[128 * 64];
  __shared__ short sB[128 * 64];
  const int lane = threadIdx.x & 63;
  const int wave = threadIdx.x >> 6;
  const int srow = lane >> 3;
  const int scol = (lane & 7) * 8;

  f32x4_t acc[4][4] = {};

  const __hip_bfloat16* aptr[4];
  const __hip_bfloat16* bptrB[4];
  const float* bptrF[4];
#pragma unroll
  for (int i = 0; i < 4; i++) {
    const int r = (wave * 4 + i) * 8 + srow;
    const int m = m0 + r;
    const int bb = m / 63;
    const int tt = m - bb * 63;
    aptr[i] = hfull + ((long)(tt + 1) * 128 + bb) * 512 + scol;
    int nrow = n0 + r;
    nrow = (nrow < V_) ? nrow : (V_ - 1);
    if constexpr (BBF16) bptrB[i] = (const __hip_bfloat16*)Bsrc + (long)nrow * 512 + scol;
    else                 bptrF[i] = (const float*)Bsrc + (long)nrow * 512 + scol;
  }

  const int wm = (wave >> 1) * 64;
  const int wn = (wave & 1) * 64;
  const int fr = lane & 15;
  const int fk = (lane >> 4) * 8;

  for (int kt = 0; kt < 8; kt++) {
    s16x8_t vb[4];
    if constexpr (!BBF16) {
#pragma unroll
      for (int i = 0; i < 4; i++) vb[i] = cvt8(bptrF[i] + kt * 64);
    }
    __syncthreads();
#pragma unroll
    for (int i = 0; i < 4; i++) {
      const int chunk = wave * 4 + i;
      gload_lds16(aptr[i] + kt * 64, sA + chunk * 512);
      if constexpr (BBF16)
        gload_lds16(bptrB[i] + kt * 64, sB + chunk * 512);
      else
        *reinterpret_cast<s16x8_t*>(sB + chunk * 512 + lane * 8) = vb[i];
    }
    __syncthreads();
#pragma unroll
    for (int kk = 0; kk < 2; kk++) {
      bf16x8_t a[4], b[4];
#pragma unroll
      for (int i = 0; i < 4; i++) {
        a[i] = lds_frag(sA + (wm + i * 16 + fr) * 64 + kk * 32 + fk);
        b[i] = lds_frag(sB + (wn + i * 16 + fr) * 64 + kk * 32 + fk);
      }
#pragma unroll
      for (int i = 0; i < 4; i++)
#pragma unroll
        for (int j = 0; j < 4; j++)
          acc[i][j] = __builtin_amdgcn_mfma_f32_16x16x32_bf16(a[i], b[j], acc[i][j], 0, 0, 0);
    }
  }

  const int fq = lane >> 4;
#pragma unroll
  for (int j = 0; j < 4; j++) {
    const int n = n0 + wn + j * 16 + fr;
    if (n >= V_) continue;
    const float bv = bias[n];
#pragma unroll
    for (int i = 0; i < 4; i++)
#pragma unroll
      for (int rr = 0; rr < 4; rr++) {
        const int m = m0 + wm + i * 16 + fq * 4 + rr;
        C[(long)m * V_ + n] = acc[i][j][rr] + bv;
      }
  }
}

// ---------------- persistent GRU scan, v8 (data-poll, no flags) ----------------
// 64 blocks = 2 halves x 32 d-strips. hfull is t-major [64][128][512]; slots
// 1..63 pre-poisoned to 0xFF (bf16 NaN; bit14 set) each call. |h| <= 1 always,
// so valid bf16 h never has bit14 set. Consumers poll their OWN A-fragment
// loads (sc0 sc1, LLC-coherent) until no halfword has bit14 -> data ready.
// Producers store h shorts sc0 sc1 fire-and-forget. No flags, no barriers,
// no release ordering: each 2B store is atomic and validated per-element.
__global__ __launch_bounds__(256) void GG_scan_persist(
    __hip_bfloat16* __restrict__ hfull,       // [64][128][512] t-major
    const __hip_bfloat16* __restrict__ gi,    // [M][G]
    const __hip_bfloat16* __restrict__ WhhB,  // [G][512] bf16
    const float* __restrict__ bhh) {          // [G] f32
  __shared__ short sW[48 * 512];      // 49,152 B, persistent all 63 steps
  const int lane = threadIdx.x & 63;
  const int wave = threadIdx.x >> 6;
  const int strip = blockIdx.x & 31;
  const int half  = blockIdx.x >> 5;
  const int d0 = strip * 16;
  const int fr = lane & 15;
  const int g4 = lane >> 4;            // 0..3

  // one-time: stage Whh strip into LDS (XOR-swizzled source granules)
  for (int rr = wave; rr < 48; rr += 4) {
    const int grow = (rr >> 4) * 512 + d0 + (rr & 15);
    gload_lds16(WhhB + (long)grow * 512 + (lane ^ (rr & 7)) * 8, sW + rr * 512);
  }

  const int dd = d0 + fr;
  const int bbase = half * 64 + wave * 16 + g4 * 4;  // epilogue rows bbase+rr
  const float br_ = bhh[dd], bz_ = bhh[512 + dd], bn_ = bhh[1024 + dd];
  const short* gis = (const short*)gi;

  // A-load base: lane reads batch row (half*64+wave*16+(l&15)), k-offset g4*8.
  // t-major: step stride = 128*512*2 = 131072 bytes.
  const int arow = half * 64 + wave * 16 + fr;
  const ull_t abase0 =
      (ull_t)hfull + ((ull_t)arow * 512 + (unsigned)(g4 * 8)) * 2ull;

  ull_t sbase[4];
  const short* gp0[4];
#pragma unroll
  for (int rr = 0; rr < 4; rr++) {
    sbase[rr] = (ull_t)hfull + ((ull_t)(bbase + rr) * 512 + (unsigned)dd) * 2ull;
    gp0[rr] = gis + (long)(bbase + rr) * T_ * G_ + dd;
  }

  // gi(0) cached loads; hp from slot 0 (prior dispatch, never poisoned)
  unsigned cr[4], cz[4], cn[4];
  float hp[4];
#pragma unroll
  for (int rr = 0; rr < 4; rr++) {
    cr[rr] = (unsigned short)gp0[rr][0];
    cz[rr] = (unsigned short)gp0[rr][512];
    cn[rr] = (unsigned short)gp0[rr][1024];
    hp[rr] = bf2f(*(const short*)&hfull[(long)(bbase + rr) * 512 + dd]);
  }

  asm volatile("s_waitcnt vmcnt(0)" ::: "memory");
  __syncthreads();  // sW fully staged (only barrier; loop is barrier-free)

  for (int t = 0; t < T_; t++) {
    // gi(t+1) prefetch: issued first; drains inside the poll's vmcnt(0)
    const int tp = (t < T_ - 1) ? (t + 1) : (T_ - 1);
    unsigned nr[4], nz[4], nn[4];
#pragma unroll
    for (int rr = 0; rr < 4; rr++) {
      const short* gp = gp0[rr] + (long)tp * G_;
      asm volatile("global_load_ushort %0, %1, off"             : "=v"(nr[rr]) : "v"(gp));
      asm volatile("global_load_ushort %0, %1, off offset:1024" : "=v"(nz[rr]) : "v"(gp));
      asm volatile("global_load_ushort %0, %1, off offset:2048" : "=v"(nn[rr]) : "v"(gp));
    }

    // ---- data-poll: load 16 A-frags, retry until no bf16 has bit14 set ----
    const ull_t ab = abase0 + (ull_t)t * 131072ull;
    f32x4_t a[16];
    while (true) {
#define ALOAD(IDX, OFF)                                                        \
      asm volatile("global_load_dwordx4 %0, %1, off offset:" #OFF " sc0 sc1"   \
                   : "=v"(a[IDX]) : "v"(ab));
      ALOAD(0, 0)    ALOAD(1, 64)   ALOAD(2, 128)  ALOAD(3, 192)
      ALOAD(4, 256)  ALOAD(5, 320)  ALOAD(6, 384)  ALOAD(7, 448)
      ALOAD(8, 512)  ALOAD(9, 576)  ALOAD(10, 640) ALOAD(11, 704)
      ALOAD(12, 768) ALOAD(13, 832) ALOAD(14, 896) ALOAD(15, 960)
#undef ALOAD
      asm volatile("s_waitcnt vmcnt(0)" ::: "memory");
      unsigned acc_or = 0;
#pragma unroll
      for (int kt = 0; kt < 16; kt++) {
        const u32x4_t u = __builtin_bit_cast(u32x4_t, a[kt]);
        acc_or |= u[0] | u[1] | u[2] | u[3];
      }
      if (__all((acc_or & 0x40004000u) == 0u)) break;
      __builtin_amdgcn_s_sleep(2);
    }
    __builtin_amdgcn_sched_barrier(0);

    f32x4_t acc[3] = {};
#pragma unroll
    for (int kt = 0; kt < 16; kt++) {
      const bf16x8_t afr = __builtin_bit_cast(bf16x8_t, a[kt]);
      const int gsw = ((kt * 4 + g4) ^ (fr & 7)) * 8;
      bf16x8_t bfr[3];
#pragma unroll
      for (int j = 0; j < 3; j++) bfr[j] = lds_frag(sW + (j * 16 + fr) * 512 + gsw);
#pragma unroll
      for (int j = 0; j < 3; j++)
        acc[j] = __builtin_amdgcn_mfma_f32_16x16x32_bf16(afr, bfr[j], acc[j], 0, 0, 0);
    }

    // fused gates; h[t+1] stores (fire-and-forget, validated by consumers)
#pragma unroll
    for (int rr = 0; rr < 4; rr++) {
      const float rg = sigmoidf_(bf2f((short)cr[rr]) + acc[0][rr] + br_);
      const float zg = sigmoidf_(bf2f((short)cz[rr]) + acc[1][rr] + bz_);
      const float ng = tanhf(bf2f((short)cn[rr]) + rg * (acc[2][rr] + bn_));
      const short hnb = f2bf((1.f - zg) * ng + zg * hp[rr]);
      hp[rr] = bf2f(hnb);
      const ull_t saddr = sbase[rr] + (ull_t)(t + 1) * 131072ull;
      const unsigned int val = (unsigned short)hnb;
      asm volatile("global_store_short %0, %1, off sc0 sc1"
                   :: "v"(saddr), "v"(val) : "memory");
    }

    // rotate gi regs (loads drained by the poll's vmcnt(0))
#pragma unroll
    for (int rr = 0; rr < 4; rr++) { cr[rr] = nr[rr]; cz[rr] = nz[rr]; cn[rr] = nn[rr]; }
  }
}

// ---------------- tail: out[LOGITS_SZ + b] = f32(len[b] - 1) ----------------
__global__ void GG_tail_kernel(const int* __restrict__ lens, float* __restrict__ out) {
  const int b = threadIdx.x;
  if (b < B_) out[LOGITS_SZ + b] = (float)(lens[b] - 1);
}

extern "C" void kernel_launch(void* const* d_in, const int* in_sizes, int n_in,
                              void* d_out, int out_size, void* d_ws, size_t ws_size,
                              hipStream_t stream) {
  const float* gf      = (const float*)d_in[0];
  const int*   cap     = (const int*)d_in[1];
  const int*   lens    = (const int*)d_in[2];
  const float* W_embed = (const float*)d_in[3];
  const float* W_init  = (const float*)d_in[4];
  const float* b_init  = (const float*)d_in[5];
  const float* W_ih    = (const float*)d_in[6];
  const float* W_hh    = (const float*)d_in[7];
  const float* b_ih    = (const float*)d_in[8];
  const float* b_hh    = (const float*)d_in[9];
  const float* W_fc    = (const float*)d_in[10];
  const float* b_fc    = (const float*)d_in[11];
  float* out = (float*)d_out;

  // d_out scratch (all consumed before the logits GEMM writes d_out):
  char* ob = (char*)d_out;
  __hip_bfloat16* gi_ws  = (__hip_bfloat16*)ob;               // [0, 24,772,608)
  __hip_bfloat16* WhhB   = (__hip_bfloat16*)(ob + 25165824);  // 1.5 MB
  __hip_bfloat16* WihB   = (__hip_bfloat16*)(ob + 27262976);  // 1.5 MB
  __hip_bfloat16* WembB  = (__hip_bfloat16*)(ob + 29360128);  // 10 MB
  __hip_bfloat16* WinitB = (__hip_bfloat16*)(ob + 40894464);  // 2 MB
  __hip_bfloat16* gfB    = (__hip_bfloat16*)(ob + 43253760);  // 0.5 MB

  // ws: hfull [64][128][512] bf16 t-major (slot 0 = h0, slot t+1 = h_t) + WfcB
  __hip_bfloat16* hfull = (__hip_bfloat16*)d_ws;
  __hip_bfloat16* WfcB  = (__hip_bfloat16*)((char*)d_ws + 8388608);
  const bool big_ws = ws_size >= (size_t)(8388608 + 10240000);

  // 0. NaN-poison h slots 1..63 (0xFF bytes -> bf16 bit14 set). MANDATORY
  //    every call: harness does not re-poison between replays, and the scan's
  //    data-poll validity test depends on stale slots being poisoned.
  hipMemsetAsync((char*)hfull + 131072, 0xFF, 8257536, stream);

  // 1. weight/input converts to bf16
  GG_cvt5<<<dim3(3908), 256, 0, stream>>>(W_hh, WhhB, W_ih, WihB, W_embed, WembB,
                                          W_init, WinitB, gf, gfB);
  if (big_ws)
    GG_cvt_kernel<<<dim3((V_ * D_ / 8 + 255) / 256), 256, 0, stream>>>(W_fc, WfcB, V_ * D_ / 8);

  // 2. h0 -> hfull slot 0 (MFMA GEMM, 4 blocks)
  GG_gemm_h0<<<dim3(4), 256, 0, stream>>>(gfB, WinitB, b_init, hfull);

  // 3. gi = gather(W_embed, cap) @ W_ih^T + b_ih
  GG_gemm_gi<<<dim3(G_ / 128, M_ / 128), 256, 0, stream>>>(WembB, cap, WihB, b_ih, gi_ws);

  // 4. GRU scan: single persistent kernel, data-poll exchange (no flags)
  GG_scan_persist<<<dim3(SCAN_NB), 256, 0, stream>>>(hfull, gi_ws, WhhB, b_hh);

  // 5. logits (XCD-banded swizzle, 5040 = 8*10*63 padded blocks)
  if (big_ws)
    GG_gemm_logits<true><<<dim3(5040), 256, 0, stream>>>(hfull, WfcB, b_fc, out);
  else
    GG_gemm_logits<false><<<dim3(5040), 256, 0, stream>>>(hfull, W_fc, b_fc, out);

  // 6. second output
  GG_tail_kernel<<<dim3(1), 128, 0, stream>>>(lens, out);
}

// Round 14
// 543.172 us; speedup vs baseline: 5.5549x; 1.0999x over previous
//
#include <hip/hip_runtime.h>
#include <hip/hip_bf16.h>

// Problem dims
#define V_    10000
#define ENC_  2048
#define D_    512
#define B_    128
#define L_    64
#define T_    63          // L-1 timesteps
#define M_    (B_ * L_ - B_)   // 8064 rows (b*63 + t)
#define G_    (3 * D_)    // 1536 gate width
#define LOGITS_SZ ((long)M_ * V_)   // 80,640,000
#define SCAN_NB 64        // 2 batch-halves x 32 d-strips

typedef __bf16 bf16x8_t __attribute__((ext_vector_type(8)));
typedef float  f32x4_t  __attribute__((ext_vector_type(4)));
typedef short  s16x8_t  __attribute__((ext_vector_type(8)));
typedef unsigned long long ull_t;

typedef __attribute__((address_space(3))) char*       lds_cptr_t;
typedef const __attribute__((address_space(1))) char* glb_cptr_t;

__device__ __forceinline__ void gload_lds16(const void* g, void* l) {
  __builtin_amdgcn_global_load_lds((glb_cptr_t)g, (lds_cptr_t)l, 16, 0, 0);
}
__device__ __forceinline__ float bf2f(short s) {
  return __uint_as_float(((unsigned)(unsigned short)s) << 16);
}
__device__ __forceinline__ short f2bf(float f) {
  __hip_bfloat16 h = __float2bfloat16(f);  // RNE
  return *reinterpret_cast<short*>(&h);
}
__device__ __forceinline__ s16x8_t cvt8(const float* p) {
  f32x4_t lo = *reinterpret_cast<const f32x4_t*>(p);
  f32x4_t hi = *reinterpret_cast<const f32x4_t*>(p + 4);
  s16x8_t r;
#pragma unroll
  for (int e = 0; e < 4; e++) { r[e] = f2bf(lo[e]); r[4 + e] = f2bf(hi[e]); }
  return r;
}
__device__ __forceinline__ float sigmoidf_(float x) {
  return 1.0f / (1.0f + __expf(-x));
}
__device__ __forceinline__ bf16x8_t lds_frag(const short* p) {
  return __builtin_bit_cast(bf16x8_t, *reinterpret_cast<const s16x8_t*>(p));
}

// ---------------- fused f32 -> bf16 converts (5 segments, 1 launch) ----------------
__global__ void GG_cvt5(const float* __restrict__ whh, __hip_bfloat16* __restrict__ dwhh,
                        const float* __restrict__ wih, __hip_bfloat16* __restrict__ dwih,
                        const float* __restrict__ wemb, __hip_bfloat16* __restrict__ dwemb,
                        const float* __restrict__ winit, __hip_bfloat16* __restrict__ dwinit,
                        const float* __restrict__ gf, __hip_bfloat16* __restrict__ dgf) {
  const int i = blockIdx.x * blockDim.x + threadIdx.x;
  const float* s; __hip_bfloat16* d; int off;
  if (i < 98304)        { s = whh;   d = dwhh;   off = i; }
  else if (i < 196608)  { s = wih;   d = dwih;   off = i - 98304; }
  else if (i < 836608)  { s = wemb;  d = dwemb;  off = i - 196608; }
  else if (i < 967680)  { s = winit; d = dwinit; off = i - 836608; }
  else                  { s = gf;    d = dgf;    off = i - 967680; }
  s16x8_t v = cvt8(s + (long)off * 8);
  *reinterpret_cast<s16x8_t*>(d + (long)off * 8) = v;
}

__global__ void GG_cvt_kernel(const float* __restrict__ src,
                              __hip_bfloat16* __restrict__ dst, int n8) {
  int i = blockIdx.x * blockDim.x + threadIdx.x;
  if (i < n8) {
    s16x8_t v = cvt8(src + (long)i * 8);
    *reinterpret_cast<s16x8_t*>(dst + (long)i * 8) = v;
  }
}

// ---------------- h0 GEMM: hfull[b][0][:] = tanh(gf @ W_init^T + b_init) ----------------
__global__ __launch_bounds__(256) void GG_gemm_h0(
    const __hip_bfloat16* __restrict__ gfB,     // [128][2048] bf16
    const __hip_bfloat16* __restrict__ WinitB,  // [512][2048] bf16
    const float* __restrict__ binit,            // [512] f32
    __hip_bfloat16* __restrict__ hfull) {       // [B][64][512]
  __shared__ short sA[128 * 64];
  __shared__ short sB[128 * 64];
  const int lane = threadIdx.x & 63;
  const int wave = threadIdx.x >> 6;
  const int n0 = blockIdx.x * 128;
  const int srow = lane >> 3;
  const int scol = (lane & 7) * 8;

  f32x4_t acc[4][4] = {};

  const __hip_bfloat16* aptr[4];
  const __hip_bfloat16* bptr[4];
#pragma unroll
  for (int i = 0; i < 4; i++) {
    const int r = (wave * 4 + i) * 8 + srow;
    aptr[i] = gfB + (long)r * ENC_ + scol;
    bptr[i] = WinitB + (long)(n0 + r) * ENC_ + scol;
  }

  const int wm = (wave >> 1) * 64;
  const int wn = (wave & 1) * 64;
  const int fr = lane & 15;
  const int fk = (lane >> 4) * 8;

  for (int kt = 0; kt < 32; kt++) {
    __syncthreads();
#pragma unroll
    for (int i = 0; i < 4; i++) {
      const int chunk = wave * 4 + i;
      gload_lds16(aptr[i] + kt * 64, sA + chunk * 512);
      gload_lds16(bptr[i] + kt * 64, sB + chunk * 512);
    }
    __syncthreads();
#pragma unroll
    for (int kk = 0; kk < 2; kk++) {
      bf16x8_t a[4], b[4];
#pragma unroll
      for (int i = 0; i < 4; i++) {
        a[i] = lds_frag(sA + (wm + i * 16 + fr) * 64 + kk * 32 + fk);
        b[i] = lds_frag(sB + (wn + i * 16 + fr) * 64 + kk * 32 + fk);
      }
#pragma unroll
      for (int i = 0; i < 4; i++)
#pragma unroll
        for (int j = 0; j < 4; j++)
          acc[i][j] = __builtin_amdgcn_mfma_f32_16x16x32_bf16(a[i], b[j], acc[i][j], 0, 0, 0);
    }
  }

  const int fq = lane >> 4;
#pragma unroll
  for (int j = 0; j < 4; j++) {
    const int n = n0 + wn + j * 16 + fr;
    const float bv = binit[n];
#pragma unroll
    for (int i = 0; i < 4; i++)
#pragma unroll
      for (int rr = 0; rr < 4; rr++) {
        const int m = wm + i * 16 + fq * 4 + rr;
        hfull[(long)m * 64 * 512 + n] = __float2bfloat16(tanhf(acc[i][j][rr] + bv));
      }
  }
}

// ---------------- gi GEMM: gi = gather(W_embed,cap) @ W_ih^T + b_ih ----------------
__global__ __launch_bounds__(256) void GG_gemm_gi(
    const __hip_bfloat16* __restrict__ WembB,  // [V][512] bf16
    const int* __restrict__ cap,               // [B][L] int32
    const __hip_bfloat16* __restrict__ WihB,   // [G][512] bf16
    const float* __restrict__ bias,            // [G] f32
    __hip_bfloat16* __restrict__ C) {          // [M][G]
  __shared__ short sA[128 * 64];
  __shared__ short sB[128 * 64];
  const int lane = threadIdx.x & 63;
  const int wave = threadIdx.x >> 6;
  const int m0 = blockIdx.y * 128;
  const int n0 = blockIdx.x * 128;
  const int srow = lane >> 3;
  const int scol = (lane & 7) * 8;

  f32x4_t acc[4][4] = {};

  const __hip_bfloat16* aptr[4];
  const __hip_bfloat16* bptr[4];
#pragma unroll
  for (int i = 0; i < 4; i++) {
    const int r = (wave * 4 + i) * 8 + srow;
    const int bt = m0 + r;
    const int bb = bt / 63;
    const int tt = bt - bb * 63;
    aptr[i] = WembB + (long)cap[bb * L_ + tt] * 512 + scol;
    bptr[i] = WihB + (long)(n0 + r) * 512 + scol;
  }

  const int wm = (wave >> 1) * 64;
  const int wn = (wave & 1) * 64;
  const int fr = lane & 15;
  const int fk = (lane >> 4) * 8;

  for (int kt = 0; kt < 8; kt++) {
    __syncthreads();
#pragma unroll
    for (int i = 0; i < 4; i++) {
      const int chunk = wave * 4 + i;
      gload_lds16(aptr[i] + kt * 64, sA + chunk * 512);
      gload_lds16(bptr[i] + kt * 64, sB + chunk * 512);
    }
    __syncthreads();
#pragma unroll
    for (int kk = 0; kk < 2; kk++) {
      bf16x8_t a[4], b[4];
#pragma unroll
      for (int i = 0; i < 4; i++) {
        a[i] = lds_frag(sA + (wm + i * 16 + fr) * 64 + kk * 32 + fk);
        b[i] = lds_frag(sB + (wn + i * 16 + fr) * 64 + kk * 32 + fk);
      }
#pragma unroll
      for (int i = 0; i < 4; i++)
#pragma unroll
        for (int j = 0; j < 4; j++)
          acc[i][j] = __builtin_amdgcn_mfma_f32_16x16x32_bf16(a[i], b[j], acc[i][j], 0, 0, 0);
    }
  }

  const int fq = lane >> 4;
#pragma unroll
  for (int j = 0; j < 4; j++) {
    const int n = n0 + wn + j * 16 + fr;
    const float bv = bias[n];
#pragma unroll
    for (int i = 0; i < 4; i++)
#pragma unroll
      for (int rr = 0; rr < 4; rr++) {
        const int m = m0 + wm + i * 16 + fq * 4 + rr;
        C[(long)m * G_ + n] = __float2bfloat16(acc[i][j][rr] + bv);
      }
  }
}

// ---------------- logits GEMM v2: 128x256 tile, 8 waves ----------------
// grid 2520 = 8 xcd * 5 nband * 63 mrows (exact); XCD owns 5 fixed n-tiles
// (1.28 MB W_fc band resident in its L2). M=128, N=256, K=512 (BK=64).
template <bool BBF16>
__global__ __launch_bounds__(512) void GG_gemm_logits(
    const __hip_bfloat16* __restrict__ hfull,  // [B][64][512]
    const void* __restrict__ Bsrc,             // W_fc bf16 or f32 [V][512]
    const float* __restrict__ bias,            // [V] f32
    float* __restrict__ C) {                   // [M][V]
  const int flat = blockIdx.x;
  const int xcd = flat & 7;
  const int s = flat >> 3;            // 0..314
  const int col = xcd * 5 + s % 5;    // 0..39
  const int row = s / 5;              // 0..62
  const int m0 = row * 128;
  const int n0 = col * 256;

  __shared__ short sA[128 * 64];  // 16 KB
  __shared__ short sB[256 * 64];  // 32 KB
  const int lane = threadIdx.x & 63;
  const int wave = threadIdx.x >> 6;  // 0..7
  const int srow = lane >> 3;
  const int scol = (lane & 7) * 8;

  f32x4_t acc[4][4] = {};

  // A chunks: wave, wave+8 (16 total). B chunks: wave+8*i, i=0..3 (32 total).
  const __hip_bfloat16* aptr[2];
#pragma unroll
  for (int i = 0; i < 2; i++) {
    const int r = (wave + i * 8) * 8 + srow;
    const int m = m0 + r;
    const int bb = m / 63;
    const int tt = m - bb * 63;
    aptr[i] = hfull + ((long)bb * 64 + tt + 1) * 512 + scol;
  }
  const __hip_bfloat16* bptrB[4];
  const float* bptrF[4];
#pragma unroll
  for (int i = 0; i < 4; i++) {
    int nrow = n0 + (wave + i * 8) * 8 + srow;
    nrow = (nrow < V_) ? nrow : (V_ - 1);
    if constexpr (BBF16) bptrB[i] = (const __hip_bfloat16*)Bsrc + (long)nrow * 512 + scol;
    else                 bptrF[i] = (const float*)Bsrc + (long)nrow * 512 + scol;
  }

  const int wm = (wave >> 2) * 64;   // 2 wave-rows
  const int wn = (wave & 3) * 64;    // 4 wave-cols
  const int fr = lane & 15;
  const int fk = (lane >> 4) * 8;

  for (int kt = 0; kt < 8; kt++) {
    s16x8_t vb[4];
    if constexpr (!BBF16) {
#pragma unroll
      for (int i = 0; i < 4; i++) vb[i] = cvt8(bptrF[i] + kt * 64);
    }
    __syncthreads();
#pragma unroll
    for (int i = 0; i < 2; i++)
      gload_lds16(aptr[i] + kt * 64, sA + (wave + i * 8) * 512);
#pragma unroll
    for (int i = 0; i < 4; i++) {
      if constexpr (BBF16)
        gload_lds16(bptrB[i] + kt * 64, sB + (wave + i * 8) * 512);
      else
        *reinterpret_cast<s16x8_t*>(sB + (wave + i * 8) * 512 + lane * 8) = vb[i];
    }
    __syncthreads();
#pragma unroll
    for (int kk = 0; kk < 2; kk++) {
      bf16x8_t a[4], b[4];
#pragma unroll
      for (int i = 0; i < 4; i++) {
        a[i] = lds_frag(sA + (wm + i * 16 + fr) * 64 + kk * 32 + fk);
        b[i] = lds_frag(sB + (wn + i * 16 + fr) * 64 + kk * 32 + fk);
      }
#pragma unroll
      for (int i = 0; i < 4; i++)
#pragma unroll
        for (int j = 0; j < 4; j++)
          acc[i][j] = __builtin_amdgcn_mfma_f32_16x16x32_bf16(a[i], b[j], acc[i][j], 0, 0, 0);
    }
  }

  const int fq = lane >> 4;
#pragma unroll
  for (int j = 0; j < 4; j++) {
    const int n = n0 + wn + j * 16 + fr;
    if (n >= V_) continue;
    const float bv = bias[n];
#pragma unroll
    for (int i = 0; i < 4; i++)
#pragma unroll
      for (int rr = 0; rr < 4; rr++) {
        const int m = m0 + wm + i * 16 + fq * 4 + rr;
        C[(long)m * V_ + n] = acc[i][j][rr] + bv;
      }
  }
}

// ---------------- persistent GRU scan (R9, proven 316 us) ----------------
__global__ __launch_bounds__(256) void GG_scan_persist(
    __hip_bfloat16* __restrict__ hfull,       // [B][64][512]
    const __hip_bfloat16* __restrict__ gi,    // [M][G]
    const __hip_bfloat16* __restrict__ WhhB,  // [G][512] bf16
    const float* __restrict__ bhh,            // [G] f32
    int* __restrict__ flagbase) {
  __shared__ short sW[48 * 512];      // 49,152 B, persistent all 63 steps
  const int lane = threadIdx.x & 63;
  const int wave = threadIdx.x >> 6;
  const int strip = blockIdx.x & 31;
  const int half  = blockIdx.x >> 5;
  const int d0 = strip * 16;
  const int fr = lane & 15;
  const int g4 = lane >> 4;            // 0..3
  int* myflags = flagbase + half * 32;

  for (int rr = wave; rr < 48; rr += 4) {
    const int grow = (rr >> 4) * 512 + d0 + (rr & 15);
    gload_lds16(WhhB + (long)grow * 512 + (lane ^ (rr & 7)) * 8, sW + rr * 512);
  }

  const int dd = d0 + fr;
  const int bbase = half * 64 + wave * 16 + g4 * 4;
  const float br_ = bhh[dd], bz_ = bhh[512 + dd], bn_ = bhh[1024 + dd];
  const short* gis = (const short*)gi;

  const int arow = half * 64 + wave * 16 + fr;
  const ull_t abase0 =
      (ull_t)hfull + ((ull_t)arow * 64 * 512 + (unsigned)(g4 * 8)) * 2ull;

  ull_t sbase[4];
  const short* gp0[4];
#pragma unroll
  for (int rr = 0; rr < 4; rr++) {
    sbase[rr] = (ull_t)hfull +
                ((ull_t)(bbase + rr) * 64 * 512 + (unsigned)dd) * 2ull;
    gp0[rr] = gis + (long)(bbase + rr) * T_ * G_ + dd;
  }

  unsigned cr[4], cz[4], cn[4];
  float hp[4];
#pragma unroll
  for (int rr = 0; rr < 4; rr++) {
    cr[rr] = (unsigned short)gp0[rr][0];
    cz[rr] = (unsigned short)gp0[rr][512];
    cn[rr] = (unsigned short)gp0[rr][1024];
    hp[rr] = bf2f(*(const short*)&hfull[((long)(bbase + rr) * 64) * 512 + dd]);
  }

  asm volatile("s_waitcnt vmcnt(0)" ::: "memory");
  __syncthreads();  // sW fully staged

  for (int t = 0; t < T_; t++) {
    if (t > 0) {
      while (true) {
        const int v = __hip_atomic_load(&myflags[lane & 31], __ATOMIC_RELAXED,
                                        __HIP_MEMORY_SCOPE_SYSTEM);
        if (__all(v >= t)) break;
        __builtin_amdgcn_s_sleep(1);
      }
    }

    const ull_t ab = abase0 + (ull_t)t * 1024ull;
    f32x4_t a[16];
#define ALOAD(IDX, OFF)                                                        \
    asm volatile("global_load_dwordx4 %0, %1, off offset:" #OFF " sc0 sc1"     \
                 : "=v"(a[IDX]) : "v"(ab));
    ALOAD(0, 0)    ALOAD(1, 64)   ALOAD(2, 128)  ALOAD(3, 192)
    ALOAD(4, 256)  ALOAD(5, 320)  ALOAD(6, 384)  ALOAD(7, 448)
    ALOAD(8, 512)  ALOAD(9, 576)  ALOAD(10, 640) ALOAD(11, 704)
    ALOAD(12, 768) ALOAD(13, 832) ALOAD(14, 896) ALOAD(15, 960)
#undef ALOAD

    const int tp = (t < T_ - 1) ? (t + 1) : (T_ - 1);
    unsigned nr[4], nz[4], nn[4];
#pragma unroll
    for (int rr = 0; rr < 4; rr++) {
      const short* gp = gp0[rr] + (long)tp * G_;
      asm volatile("global_load_ushort %0, %1, off"             : "=v"(nr[rr]) : "v"(gp));
      asm volatile("global_load_ushort %0, %1, off offset:1024" : "=v"(nz[rr]) : "v"(gp));
      asm volatile("global_load_ushort %0, %1, off offset:2048" : "=v"(nn[rr]) : "v"(gp));
    }

    asm volatile("s_waitcnt vmcnt(12)" ::: "memory");
    __builtin_amdgcn_sched_barrier(0);

    f32x4_t acc[3] = {};
#pragma unroll
    for (int kt = 0; kt < 16; kt++) {
      const bf16x8_t afr = __builtin_bit_cast(bf16x8_t, a[kt]);
      const int gsw = ((kt * 4 + g4) ^ (fr & 7)) * 8;
      bf16x8_t bfr[3];
#pragma unroll
      for (int j = 0; j < 3; j++) bfr[j] = lds_frag(sW + (j * 16 + fr) * 512 + gsw);
#pragma unroll
      for (int j = 0; j < 3; j++)
        acc[j] = __builtin_amdgcn_mfma_f32_16x16x32_bf16(afr, bfr[j], acc[j], 0, 0, 0);
    }

#pragma unroll
    for (int rr = 0; rr < 4; rr++) {
      const float rg = sigmoidf_(bf2f((short)cr[rr]) + acc[0][rr] + br_);
      const float zg = sigmoidf_(bf2f((short)cz[rr]) + acc[1][rr] + bz_);
      const float ng = tanhf(bf2f((short)cn[rr]) + rg * (acc[2][rr] + bn_));
      const short hnb = f2bf((1.f - zg) * ng + zg * hp[rr]);
      hp[rr] = bf2f(hnb);
      const ull_t saddr = sbase[rr] + (ull_t)(t + 1) * 1024ull;
      const unsigned int val = (unsigned short)hnb;
      asm volatile("global_store_short %0, %1, off sc0 sc1"
                   :: "v"(saddr), "v"(val) : "memory");
    }

    asm volatile("s_waitcnt vmcnt(0)" ::: "memory");
    __builtin_amdgcn_sched_barrier(0);
#pragma unroll
    for (int rr = 0; rr < 4; rr++) { cr[rr] = nr[rr]; cz[rr] = nz[rr]; cn[rr] = nn[rr]; }

    if (t < T_ - 1) {
      __syncthreads();
      if (threadIdx.x == 0)
        __hip_atomic_store(&myflags[strip], t + 1, __ATOMIC_RELAXED,
                           __HIP_MEMORY_SCOPE_SYSTEM);
    }
  }
}

// ---------------- tail: out[LOGITS_SZ + b] = f32(len[b] - 1) ----------------
__global__ void GG_tail_kernel(const int* __restrict__ lens, float* __restrict__ out) {
  const int b = threadIdx.x;
  if (b < B_) out[LOGITS_SZ + b] = (float)(lens[b] - 1);
}

extern "C" void kernel_launch(void* const* d_in, const int* in_sizes, int n_in,
                              void* d_out, int out_size, void* d_ws, size_t ws_size,
                              hipStream_t stream) {
  const float* gf      = (const float*)d_in[0];
  const int*   cap     = (const int*)d_in[1];
  const int*   lens    = (const int*)d_in[2];
  const float* W_embed = (const float*)d_in[3];
  const float* W_init  = (const float*)d_in[4];
  const float* b_init  = (const float*)d_in[5];
  const float* W_ih    = (const float*)d_in[6];
  const float* W_hh    = (const float*)d_in[7];
  const float* b_ih    = (const float*)d_in[8];
  const float* b_hh    = (const float*)d_in[9];
  const float* W_fc    = (const float*)d_in[10];
  const float* b_fc    = (const float*)d_in[11];
  float* out = (float*)d_out;

  // d_out scratch (all consumed before the logits GEMM writes d_out):
  char* ob = (char*)d_out;
  __hip_bfloat16* gi_ws  = (__hip_bfloat16*)ob;               // [0, 24,772,608)
  __hip_bfloat16* WhhB   = (__hip_bfloat16*)(ob + 25165824);  // 1.5 MB
  __hip_bfloat16* WihB   = (__hip_bfloat16*)(ob + 27262976);  // 1.5 MB
  __hip_bfloat16* WembB  = (__hip_bfloat16*)(ob + 29360128);  // 10 MB
  __hip_bfloat16* WinitB = (__hip_bfloat16*)(ob + 40894464);  // 2 MB
  __hip_bfloat16* gfB    = (__hip_bfloat16*)(ob + 43253760);  // 0.5 MB

  // ws: hfull [B][64][512] bf16 (slot 0 = h0, slot t+1 = h_t) + WfcB + flags
  __hip_bfloat16* hfull = (__hip_bfloat16*)d_ws;
  __hip_bfloat16* WfcB  = (__hip_bfloat16*)((char*)d_ws + 8388608);
  const bool big_ws = ws_size >= (size_t)(8388608 + 10240000 + 256);
  int* flags = (int*)((char*)d_ws + (big_ws ? 18628608 : 8388608));

  // 0. reset barrier flags (graph-replayed every call -> deterministic)
  hipMemsetAsync(flags, 0, 256, stream);

  // 1. weight/input converts to bf16 (fused: 3908 * 256 covers all 5 segments)
  GG_cvt5<<<dim3(3908), 256, 0, stream>>>(W_hh, WhhB, W_ih, WihB, W_embed, WembB,
                                          W_init, WinitB, gf, gfB);
  if (big_ws)
    GG_cvt_kernel<<<dim3((V_ * D_ / 8 + 255) / 256), 256, 0, stream>>>(W_fc, WfcB, V_ * D_ / 8);

  // 2. h0 -> hfull slot 0 (MFMA GEMM, 4 blocks)
  GG_gemm_h0<<<dim3(4), 256, 0, stream>>>(gfB, WinitB, b_init, hfull);

  // 3. gi = gather(W_embed, cap) @ W_ih^T + b_ih
  GG_gemm_gi<<<dim3(G_ / 128, M_ / 128), 256, 0, stream>>>(WembB, cap, WihB, b_ih, gi_ws);

  // 4. GRU scan: single persistent kernel (R9 protocol)
  GG_scan_persist<<<dim3(SCAN_NB), 256, 0, stream>>>(hfull, gi_ws, WhhB, b_hh, flags);

  // 5. logits: 128x256 tile, 8 waves, XCD-banded (2520 = 8*5*63 exact)
  if (big_ws)
    GG_gemm_logits<true><<<dim3(2520), 512, 0, stream>>>(hfull, WfcB, b_fc, out);
  else
    GG_gemm_logits<false><<<dim3(2520), 512, 0, stream>>>(hfull, W_fc, b_fc, out);

  // 6. second output
  GG_tail_kernel<<<dim3(1), 128, 0, stream>>>(lens, out);
}

// Round 15
// 516.691 us; speedup vs baseline: 5.8396x; 1.0513x over previous
//
#include <hip/hip_runtime.h>
#include <hip/hip_bf16.h>

// Problem dims
#define V_    10000
#define ENC_  2048
#define D_    512
#define B_    128
#define L_    64
#define T_    63          // L-1 timesteps
#define M_    (B_ * L_ - B_)   // 8064 rows (b*63 + t)
#define G_    (3 * D_)    // 1536 gate width
#define LOGITS_SZ ((long)M_ * V_)   // 80,640,000
#define SCAN_NB 64        // 2 batch-halves x 32 d-strips

typedef __bf16 bf16x8_t __attribute__((ext_vector_type(8)));
typedef float  f32x4_t  __attribute__((ext_vector_type(4)));
typedef short  s16x8_t  __attribute__((ext_vector_type(8)));
typedef unsigned long long ull_t;

typedef __attribute__((address_space(3))) char*       lds_cptr_t;
typedef const __attribute__((address_space(1))) char* glb_cptr_t;

__device__ __forceinline__ void gload_lds16(const void* g, void* l) {
  __builtin_amdgcn_global_load_lds((glb_cptr_t)g, (lds_cptr_t)l, 16, 0, 0);
}
__device__ __forceinline__ float bf2f(short s) {
  return __uint_as_float(((unsigned)(unsigned short)s) << 16);
}
__device__ __forceinline__ short f2bf(float f) {
  __hip_bfloat16 h = __float2bfloat16(f);  // RNE
  return *reinterpret_cast<short*>(&h);
}
__device__ __forceinline__ s16x8_t cvt8(const float* p) {
  f32x4_t lo = *reinterpret_cast<const f32x4_t*>(p);
  f32x4_t hi = *reinterpret_cast<const f32x4_t*>(p + 4);
  s16x8_t r;
#pragma unroll
  for (int e = 0; e < 4; e++) { r[e] = f2bf(lo[e]); r[4 + e] = f2bf(hi[e]); }
  return r;
}
__device__ __forceinline__ float sigmoidf_(float x) {
  return 1.0f / (1.0f + __expf(-x));
}
__device__ __forceinline__ bf16x8_t lds_frag(const short* p) {
  return __builtin_bit_cast(bf16x8_t, *reinterpret_cast<const s16x8_t*>(p));
}

// ---------------- fused f32 -> bf16 converts (6 segments, 1 launch) ----------------
// n8 ranges: Whh [0,98304) Wih [98304,196608) Wemb [196608,836608)
// Winit [836608,967680) gf [967680,1000448) Wfc [1000448,1640448) (optional)
__global__ void GG_cvt6(const float* __restrict__ whh, __hip_bfloat16* __restrict__ dwhh,
                        const float* __restrict__ wih, __hip_bfloat16* __restrict__ dwih,
                        const float* __restrict__ wemb, __hip_bfloat16* __restrict__ dwemb,
                        const float* __restrict__ winit, __hip_bfloat16* __restrict__ dwinit,
                        const float* __restrict__ gf, __hip_bfloat16* __restrict__ dgf,
                        const float* __restrict__ wfc, __hip_bfloat16* __restrict__ dwfc) {
  const int i = blockIdx.x * blockDim.x + threadIdx.x;
  const float* s; __hip_bfloat16* d; int off;
  if (i < 98304)        { s = whh;   d = dwhh;   off = i; }
  else if (i < 196608)  { s = wih;   d = dwih;   off = i - 98304; }
  else if (i < 836608)  { s = wemb;  d = dwemb;  off = i - 196608; }
  else if (i < 967680)  { s = winit; d = dwinit; off = i - 836608; }
  else if (i < 1000448) { s = gf;    d = dgf;    off = i - 967680; }
  else {
    if (dwfc == nullptr || i >= 1640448) return;
    s = wfc; d = dwfc; off = i - 1000448;
  }
  s16x8_t v = cvt8(s + (long)off * 8);
  *reinterpret_cast<s16x8_t*>(d + (long)off * 8) = v;
}

// ---------------- h0 GEMM: hfull[b][0][:] = tanh(gf @ W_init^T + b_init) ----------------
// T2-swizzled staging: pre-swizzled global source granule, linear LDS dest.
__global__ __launch_bounds__(256) void GG_gemm_h0(
    const __hip_bfloat16* __restrict__ gfB,     // [128][2048] bf16
    const __hip_bfloat16* __restrict__ WinitB,  // [512][2048] bf16
    const float* __restrict__ binit,            // [512] f32
    __hip_bfloat16* __restrict__ hfull) {       // [B][64][512]
  __shared__ short sA[128 * 64];
  __shared__ short sB[128 * 64];
  const int lane = threadIdx.x & 63;
  const int wave = threadIdx.x >> 6;
  const int n0 = blockIdx.x * 128;
  const int srow = lane >> 3;
  const int scolz = ((lane & 7) ^ (srow & 7)) * 8;  // swizzled source granule

  f32x4_t acc[4][4] = {};

  const __hip_bfloat16* aptr[4];
  const __hip_bfloat16* bptr[4];
#pragma unroll
  for (int i = 0; i < 4; i++) {
    const int r = (wave * 4 + i) * 8 + srow;
    aptr[i] = gfB + (long)r * ENC_ + scolz;
    bptr[i] = WinitB + (long)(n0 + r) * ENC_ + scolz;
  }

  const int wm = (wave >> 1) * 64;
  const int wn = (wave & 1) * 64;
  const int fr = lane & 15;
  const int g4 = lane >> 4;

  for (int kt = 0; kt < 32; kt++) {
    __syncthreads();
#pragma unroll
    for (int i = 0; i < 4; i++) {
      const int chunk = wave * 4 + i;
      gload_lds16(aptr[i] + kt * 64, sA + chunk * 512);
      gload_lds16(bptr[i] + kt * 64, sB + chunk * 512);
    }
    __syncthreads();
#pragma unroll
    for (int kk = 0; kk < 2; kk++) {
      const int gsw = ((kk * 4 + g4) ^ (fr & 7)) * 8;
      bf16x8_t a[4], b[4];
#pragma unroll
      for (int i = 0; i < 4; i++) {
        a[i] = lds_frag(sA + (wm + i * 16 + fr) * 64 + gsw);
        b[i] = lds_frag(sB + (wn + i * 16 + fr) * 64 + gsw);
      }
#pragma unroll
      for (int i = 0; i < 4; i++)
#pragma unroll
        for (int j = 0; j < 4; j++)
          acc[i][j] = __builtin_amdgcn_mfma_f32_16x16x32_bf16(a[i], b[j], acc[i][j], 0, 0, 0);
    }
  }

  const int fq = lane >> 4;
#pragma unroll
  for (int j = 0; j < 4; j++) {
    const int n = n0 + wn + j * 16 + fr;
    const float bv = binit[n];
#pragma unroll
    for (int i = 0; i < 4; i++)
#pragma unroll
      for (int rr = 0; rr < 4; rr++) {
        const int m = wm + i * 16 + fq * 4 + rr;
        hfull[(long)m * 64 * 512 + n] = __float2bfloat16(tanhf(acc[i][j][rr] + bv));
      }
  }
}

// ---------------- gi GEMM: gi = gather(W_embed,cap) @ W_ih^T + b_ih ----------------
// T2-swizzled staging (both operands bf16 via gload).
__global__ __launch_bounds__(256) void GG_gemm_gi(
    const __hip_bfloat16* __restrict__ WembB,  // [V][512] bf16
    const int* __restrict__ cap,               // [B][L] int32
    const __hip_bfloat16* __restrict__ WihB,   // [G][512] bf16
    const float* __restrict__ bias,            // [G] f32
    __hip_bfloat16* __restrict__ C) {          // [M][G]
  __shared__ short sA[128 * 64];
  __shared__ short sB[128 * 64];
  const int lane = threadIdx.x & 63;
  const int wave = threadIdx.x >> 6;
  const int m0 = blockIdx.y * 128;
  const int n0 = blockIdx.x * 128;
  const int srow = lane >> 3;
  const int scolz = ((lane & 7) ^ (srow & 7)) * 8;

  f32x4_t acc[4][4] = {};

  const __hip_bfloat16* aptr[4];
  const __hip_bfloat16* bptr[4];
#pragma unroll
  for (int i = 0; i < 4; i++) {
    const int r = (wave * 4 + i) * 8 + srow;
    const int bt = m0 + r;
    const int bb = bt / 63;
    const int tt = bt - bb * 63;
    aptr[i] = WembB + (long)cap[bb * L_ + tt] * 512 + scolz;
    bptr[i] = WihB + (long)(n0 + r) * 512 + scolz;
  }

  const int wm = (wave >> 1) * 64;
  const int wn = (wave & 1) * 64;
  const int fr = lane & 15;
  const int g4 = lane >> 4;

  for (int kt = 0; kt < 8; kt++) {
    __syncthreads();
#pragma unroll
    for (int i = 0; i < 4; i++) {
      const int chunk = wave * 4 + i;
      gload_lds16(aptr[i] + kt * 64, sA + chunk * 512);
      gload_lds16(bptr[i] + kt * 64, sB + chunk * 512);
    }
    __syncthreads();
#pragma unroll
    for (int kk = 0; kk < 2; kk++) {
      const int gsw = ((kk * 4 + g4) ^ (fr & 7)) * 8;
      bf16x8_t a[4], b[4];
#pragma unroll
      for (int i = 0; i < 4; i++) {
        a[i] = lds_frag(sA + (wm + i * 16 + fr) * 64 + gsw);
        b[i] = lds_frag(sB + (wn + i * 16 + fr) * 64 + gsw);
      }
#pragma unroll
      for (int i = 0; i < 4; i++)
#pragma unroll
        for (int j = 0; j < 4; j++)
          acc[i][j] = __builtin_amdgcn_mfma_f32_16x16x32_bf16(a[i], b[j], acc[i][j], 0, 0, 0);
    }
  }

  const int fq = lane >> 4;
#pragma unroll
  for (int j = 0; j < 4; j++) {
    const int n = n0 + wn + j * 16 + fr;
    const float bv = bias[n];
#pragma unroll
    for (int i = 0; i < 4; i++)
#pragma unroll
      for (int rr = 0; rr < 4; rr++) {
        const int m = m0 + wm + i * 16 + fq * 4 + rr;
        C[(long)m * G_ + n] = __float2bfloat16(acc[i][j][rr] + bv);
      }
  }
}

// ---------------- logits GEMM v3: 128x256 tile, 8 waves, T2-swizzled ----------------
// grid 2520 = 8 xcd * 5 nband * 63 mrows (exact); XCD owns 5 fixed n-tiles.
template <bool BBF16>
__global__ __launch_bounds__(512) void GG_gemm_logits(
    const __hip_bfloat16* __restrict__ hfull,  // [B][64][512]
    const void* __restrict__ Bsrc,             // W_fc bf16 or f32 [V][512]
    const float* __restrict__ bias,            // [V] f32
    float* __restrict__ C) {                   // [M][V]
  const int flat = blockIdx.x;
  const int xcd = flat & 7;
  const int s = flat >> 3;            // 0..314
  const int col = xcd * 5 + s % 5;    // 0..39
  const int row = s / 5;              // 0..62
  const int m0 = row * 128;
  const int n0 = col * 256;

  __shared__ short sA[128 * 64];  // 16 KB
  __shared__ short sB[256 * 64];  // 32 KB
  const int lane = threadIdx.x & 63;
  const int wave = threadIdx.x >> 6;  // 0..7
  const int srow = lane >> 3;
  const int scol  = (lane & 7) * 8;                 // linear source granule
  const int scolz = ((lane & 7) ^ (srow & 7)) * 8;  // swizzled source granule

  f32x4_t acc[4][4] = {};

  // A chunks: wave, wave+8 (16 total). B chunks: wave+8*i, i=0..3 (32 total).
  const __hip_bfloat16* aptr[2];
#pragma unroll
  for (int i = 0; i < 2; i++) {
    const int r = (wave + i * 8) * 8 + srow;
    const int m = m0 + r;
    const int bb = m / 63;
    const int tt = m - bb * 63;
    aptr[i] = hfull + ((long)bb * 64 + tt + 1) * 512 + scolz;
  }
  const __hip_bfloat16* bptrB[4];
  const float* bptrF[4];
#pragma unroll
  for (int i = 0; i < 4; i++) {
    int nrow = n0 + (wave + i * 8) * 8 + srow;
    nrow = (nrow < V_) ? nrow : (V_ - 1);
    if constexpr (BBF16) bptrB[i] = (const __hip_bfloat16*)Bsrc + (long)nrow * 512 + scolz;
    else                 bptrF[i] = (const float*)Bsrc + (long)nrow * 512 + scol;
  }

  const int wm = (wave >> 2) * 64;   // 2 wave-rows
  const int wn = (wave & 3) * 64;    // 4 wave-cols
  const int fr = lane & 15;
  const int g4 = lane >> 4;

  for (int kt = 0; kt < 8; kt++) {
    s16x8_t vb[4];
    if constexpr (!BBF16) {
#pragma unroll
      for (int i = 0; i < 4; i++) vb[i] = cvt8(bptrF[i] + kt * 64);
    }
    __syncthreads();
#pragma unroll
    for (int i = 0; i < 2; i++)
      gload_lds16(aptr[i] + kt * 64, sA + (wave + i * 8) * 512);
#pragma unroll
    for (int i = 0; i < 4; i++) {
      if constexpr (BBF16)
        gload_lds16(bptrB[i] + kt * 64, sB + (wave + i * 8) * 512);
      else  // reg-staged: linear source, swizzled ds_write dest slot
        *reinterpret_cast<s16x8_t*>(
            sB + (wave + i * 8) * 512 + srow * 64 + (((lane & 7) ^ (srow & 7)) * 8)) = vb[i];
    }
    __syncthreads();
#pragma unroll
    for (int kk = 0; kk < 2; kk++) {
      const int gsw = ((kk * 4 + g4) ^ (fr & 7)) * 8;
      bf16x8_t a[4], b[4];
#pragma unroll
      for (int i = 0; i < 4; i++) {
        a[i] = lds_frag(sA + (wm + i * 16 + fr) * 64 + gsw);
        b[i] = lds_frag(sB + (wn + i * 16 + fr) * 64 + gsw);
      }
#pragma unroll
      for (int i = 0; i < 4; i++)
#pragma unroll
        for (int j = 0; j < 4; j++)
          acc[i][j] = __builtin_amdgcn_mfma_f32_16x16x32_bf16(a[i], b[j], acc[i][j], 0, 0, 0);
    }
  }

  const int fq = lane >> 4;
#pragma unroll
  for (int j = 0; j < 4; j++) {
    const int n = n0 + wn + j * 16 + fr;
    if (n >= V_) continue;
    const float bv = bias[n];
#pragma unroll
    for (int i = 0; i < 4; i++)
#pragma unroll
      for (int rr = 0; rr < 4; rr++) {
        const int m = m0 + wm + i * 16 + fq * 4 + rr;
        C[(long)m * V_ + n] = acc[i][j][rr] + bv;
      }
  }
}

// ---------------- persistent GRU scan (R9, proven 316 us) ----------------
__global__ __launch_bounds__(256) void GG_scan_persist(
    __hip_bfloat16* __restrict__ hfull,       // [B][64][512]
    const __hip_bfloat16* __restrict__ gi,    // [M][G]
    const __hip_bfloat16* __restrict__ WhhB,  // [G][512] bf16
    const float* __restrict__ bhh,            // [G] f32
    int* __restrict__ flagbase) {
  __shared__ short sW[48 * 512];      // 49,152 B, persistent all 63 steps
  const int lane = threadIdx.x & 63;
  const int wave = threadIdx.x >> 6;
  const int strip = blockIdx.x & 31;
  const int half  = blockIdx.x >> 5;
  const int d0 = strip * 16;
  const int fr = lane & 15;
  const int g4 = lane >> 4;            // 0..3
  int* myflags = flagbase + half * 32;

  for (int rr = wave; rr < 48; rr += 4) {
    const int grow = (rr >> 4) * 512 + d0 + (rr & 15);
    gload_lds16(WhhB + (long)grow * 512 + (lane ^ (rr & 7)) * 8, sW + rr * 512);
  }

  const int dd = d0 + fr;
  const int bbase = half * 64 + wave * 16 + g4 * 4;
  const float br_ = bhh[dd], bz_ = bhh[512 + dd], bn_ = bhh[1024 + dd];
  const short* gis = (const short*)gi;

  const int arow = half * 64 + wave * 16 + fr;
  const ull_t abase0 =
      (ull_t)hfull + ((ull_t)arow * 64 * 512 + (unsigned)(g4 * 8)) * 2ull;

  ull_t sbase[4];
  const short* gp0[4];
#pragma unroll
  for (int rr = 0; rr < 4; rr++) {
    sbase[rr] = (ull_t)hfull +
                ((ull_t)(bbase + rr) * 64 * 512 + (unsigned)dd) * 2ull;
    gp0[rr] = gis + (long)(bbase + rr) * T_ * G_ + dd;
  }

  unsigned cr[4], cz[4], cn[4];
  float hp[4];
#pragma unroll
  for (int rr = 0; rr < 4; rr++) {
    cr[rr] = (unsigned short)gp0[rr][0];
    cz[rr] = (unsigned short)gp0[rr][512];
    cn[rr] = (unsigned short)gp0[rr][1024];
    hp[rr] = bf2f(*(const short*)&hfull[((long)(bbase + rr) * 64) * 512 + dd]);
  }

  asm volatile("s_waitcnt vmcnt(0)" ::: "memory");
  __syncthreads();  // sW fully staged

  for (int t = 0; t < T_; t++) {
    if (t > 0) {
      while (true) {
        const int v = __hip_atomic_load(&myflags[lane & 31], __ATOMIC_RELAXED,
                                        __HIP_MEMORY_SCOPE_SYSTEM);
        if (__all(v >= t)) break;
        __builtin_amdgcn_s_sleep(1);
      }
    }

    const ull_t ab = abase0 + (ull_t)t * 1024ull;
    f32x4_t a[16];
#define ALOAD(IDX, OFF)                                                        \
    asm volatile("global_load_dwordx4 %0, %1, off offset:" #OFF " sc0 sc1"     \
                 : "=v"(a[IDX]) : "v"(ab));
    ALOAD(0, 0)    ALOAD(1, 64)   ALOAD(2, 128)  ALOAD(3, 192)
    ALOAD(4, 256)  ALOAD(5, 320)  ALOAD(6, 384)  ALOAD(7, 448)
    ALOAD(8, 512)  ALOAD(9, 576)  ALOAD(10, 640) ALOAD(11, 704)
    ALOAD(12, 768) ALOAD(13, 832) ALOAD(14, 896) ALOAD(15, 960)
#undef ALOAD

    const int tp = (t < T_ - 1) ? (t + 1) : (T_ - 1);
    unsigned nr[4], nz[4], nn[4];
#pragma unroll
    for (int rr = 0; rr < 4; rr++) {
      const short* gp = gp0[rr] + (long)tp * G_;
      asm volatile("global_load_ushort %0, %1, off"             : "=v"(nr[rr]) : "v"(gp));
      asm volatile("global_load_ushort %0, %1, off offset:1024" : "=v"(nz[rr]) : "v"(gp));
      asm volatile("global_load_ushort %0, %1, off offset:2048" : "=v"(nn[rr]) : "v"(gp));
    }

    asm volatile("s_waitcnt vmcnt(12)" ::: "memory");
    __builtin_amdgcn_sched_barrier(0);

    f32x4_t acc[3] = {};
#pragma unroll
    for (int kt = 0; kt < 16; kt++) {
      const bf16x8_t afr = __builtin_bit_cast(bf16x8_t, a[kt]);
      const int gsw = ((kt * 4 + g4) ^ (fr & 7)) * 8;
      bf16x8_t bfr[3];
#pragma unroll
      for (int j = 0; j < 3; j++) bfr[j] = lds_frag(sW + (j * 16 + fr) * 512 + gsw);
#pragma unroll
      for (int j = 0; j < 3; j++)
        acc[j] = __builtin_amdgcn_mfma_f32_16x16x32_bf16(afr, bfr[j], acc[j], 0, 0, 0);
    }

#pragma unroll
    for (int rr = 0; rr < 4; rr++) {
      const float rg = sigmoidf_(bf2f((short)cr[rr]) + acc[0][rr] + br_);
      const float zg = sigmoidf_(bf2f((short)cz[rr]) + acc[1][rr] + bz_);
      const float ng = tanhf(bf2f((short)cn[rr]) + rg * (acc[2][rr] + bn_));
      const short hnb = f2bf((1.f - zg) * ng + zg * hp[rr]);
      hp[rr] = bf2f(hnb);
      const ull_t saddr = sbase[rr] + (ull_t)(t + 1) * 1024ull;
      const unsigned int val = (unsigned short)hnb;
      asm volatile("global_store_short %0, %1, off sc0 sc1"
                   :: "v"(saddr), "v"(val) : "memory");
    }

    asm volatile("s_waitcnt vmcnt(0)" ::: "memory");
    __builtin_amdgcn_sched_barrier(0);
#pragma unroll
    for (int rr = 0; rr < 4; rr++) { cr[rr] = nr[rr]; cz[rr] = nz[rr]; cn[rr] = nn[rr]; }

    if (t < T_ - 1) {
      __syncthreads();
      if (threadIdx.x == 0)
        __hip_atomic_store(&myflags[strip], t + 1, __ATOMIC_RELAXED,
                           __HIP_MEMORY_SCOPE_SYSTEM);
    }
  }
}

// ---------------- tail: out[LOGITS_SZ + b] = f32(len[b] - 1) ----------------
__global__ void GG_tail_kernel(const int* __restrict__ lens, float* __restrict__ out) {
  const int b = threadIdx.x;
  if (b < B_) out[LOGITS_SZ + b] = (float)(lens[b] - 1);
}

extern "C" void kernel_launch(void* const* d_in, const int* in_sizes, int n_in,
                              void* d_out, int out_size, void* d_ws, size_t ws_size,
                              hipStream_t stream) {
  const float* gf      = (const float*)d_in[0];
  const int*   cap     = (const int*)d_in[1];
  const int*   lens    = (const int*)d_in[2];
  const float* W_embed = (const float*)d_in[3];
  const float* W_init  = (const float*)d_in[4];
  const float* b_init  = (const float*)d_in[5];
  const float* W_ih    = (const float*)d_in[6];
  const float* W_hh    = (const float*)d_in[7];
  const float* b_ih    = (const float*)d_in[8];
  const float* b_hh    = (const float*)d_in[9];
  const float* W_fc    = (const float*)d_in[10];
  const float* b_fc    = (const float*)d_in[11];
  float* out = (float*)d_out;

  // d_out scratch (all consumed before the logits GEMM writes d_out):
  char* ob = (char*)d_out;
  __hip_bfloat16* gi_ws  = (__hip_bfloat16*)ob;               // [0, 24,772,608)
  __hip_bfloat16* WhhB   = (__hip_bfloat16*)(ob + 25165824);  // 1.5 MB
  __hip_bfloat16* WihB   = (__hip_bfloat16*)(ob + 27262976);  // 1.5 MB
  __hip_bfloat16* WembB  = (__hip_bfloat16*)(ob + 29360128);  // 10 MB
  __hip_bfloat16* WinitB = (__hip_bfloat16*)(ob + 40894464);  // 2 MB
  __hip_bfloat16* gfB    = (__hip_bfloat16*)(ob + 43253760);  // 0.5 MB

  // ws: hfull [B][64][512] bf16 (slot 0 = h0, slot t+1 = h_t) + WfcB + flags
  __hip_bfloat16* hfull = (__hip_bfloat16*)d_ws;
  __hip_bfloat16* WfcB  = (__hip_bfloat16*)((char*)d_ws + 8388608);
  const bool big_ws = ws_size >= (size_t)(8388608 + 10240000 + 256);
  int* flags = (int*)((char*)d_ws + (big_ws ? 18628608 : 8388608));

  // 0. reset barrier flags (graph-replayed every call -> deterministic)
  hipMemsetAsync(flags, 0, 256, stream);

  // 1. all weight/input converts in ONE launch (Wfc segment guarded)
  GG_cvt6<<<dim3(6408), 256, 0, stream>>>(W_hh, WhhB, W_ih, WihB, W_embed, WembB,
                                          W_init, WinitB, gf, gfB,
                                          W_fc, big_ws ? WfcB : nullptr);

  // 2. h0 -> hfull slot 0 (MFMA GEMM, 4 blocks)
  GG_gemm_h0<<<dim3(4), 256, 0, stream>>>(gfB, WinitB, b_init, hfull);

  // 3. gi = gather(W_embed, cap) @ W_ih^T + b_ih
  GG_gemm_gi<<<dim3(G_ / 128, M_ / 128), 256, 0, stream>>>(WembB, cap, WihB, b_ih, gi_ws);

  // 4. GRU scan: single persistent kernel (R9 protocol)
  GG_scan_persist<<<dim3(SCAN_NB), 256, 0, stream>>>(hfull, gi_ws, WhhB, b_hh, flags);

  // 5. logits: 128x256 tile, 8 waves, XCD-banded, T2-swizzled
  if (big_ws)
    GG_gemm_logits<true><<<dim3(2520), 512, 0, stream>>>(hfull, WfcB, b_fc, out);
  else
    GG_gemm_logits<false><<<dim3(2520), 512, 0, stream>>>(hfull, W_fc, b_fc, out);

  // 6. second output
  GG_tail_kernel<<<dim3(1), 128, 0, stream>>>(lens, out);
}